// Round 10
// baseline (130.497 us; speedup 1.0000x reference)
//
#include <hip/hip_runtime.h>
#include <hip/hip_fp8.h>
#include <math.h>

#define BSZ   8192
#define NCLS  57
#define DIM   256
#define NTASK 57
#define INV_T (1.0f/0.07f)
#define GBM   64                 // row tiles (128 rows each)
#define GBN   32                 // col tiles (256 cols each)
#define FIN_GRID 32

typedef float f32x4 __attribute__((ext_vector_type(4)));
typedef long  lgx2  __attribute__((ext_vector_type(2)));

// async global->LDS, 16B per lane; l must be wave-uniform base (HW adds lane*16)
__device__ __forceinline__ void gload_lds16(const void* g, void* l) {
    __builtin_amdgcn_global_load_lds(
        (const __attribute__((address_space(1))) unsigned int*)g,
        (__attribute__((address_space(3))) unsigned int*)l, 16, 0, 0);
}

// ---- kernel 1: fused logits stats + normalize->fp8 (K-interleaved) -----------------
// fp8 K-layout: k' = (ks>>1)*64 + g*16 + (ks&1)*8 + b  for original k = ks*32+g*8+b
// (verified R9): makes A/B fragment reads pure b128.
__global__ __launch_bounds__(256) void k_prep(
        const float* __restrict__ logits, const float* __restrict__ emb,
        const int* __restrict__ labels, const int* __restrict__ tasks,
        float* __restrict__ u, float* __restrict__ cls_part,
        int* __restrict__ task_count, unsigned char* __restrict__ e) {
    __shared__ float scls[4];
    int wave = threadIdx.x >> 6;
    int lane = threadIdx.x & 63;
    int row  = blockIdx.x * 4 + wave;

    // --- logits: softmax stats ---
    float v = (lane < NCLS) ? logits[row * NCLS + lane] : -3.0e38f;
    float m = v;
    #pragma unroll
    for (int s = 1; s < 64; s <<= 1) m = fmaxf(m, __shfl_xor(m, s));
    float ex = (lane < NCLS) ? __expf(v - m) : 0.0f;
    float se = ex;
    #pragma unroll
    for (int s = 1; s < 64; s <<= 1) se += __shfl_xor(se, s);
    float lse = m + logf(se);
    float p = ex / se;
    float term = (lane < NCLS) ? p * logf(p + 1e-8f) : 0.0f;
    float ent = term;
    #pragma unroll
    for (int s = 1; s < 64; s <<= 1) ent += __shfl_xor(ent, s);
    ent = -ent;
    int lab = labels[row];
    float vl = __shfl(v, lab);           // logits[row][label]
    float cls = lse - vl;                // -log_softmax[label]

    // --- embeddings: L2-normalize -> fp8 e4m3, K-interleaved store ---
    const float4* src = reinterpret_cast<const float4*>(emb + (size_t)row * DIM);
    float4 x = src[lane];
    float ss = x.x*x.x + x.y*x.y + x.z*x.z + x.w*x.w;
    #pragma unroll
    for (int s = 1; s < 64; s <<= 1) ss += __shfl_xor(ss, s);
    float sc = 1.0f / fmaxf(sqrtf(ss), 1e-12f);
    __hip_fp8_e4m3 f0(x.x * sc), f1(x.y * sc), f2(x.z * sc), f3(x.w * sc);
    uchar4 o;
    o.x = *reinterpret_cast<unsigned char*>(&f0);
    o.y = *reinterpret_cast<unsigned char*>(&f1);
    o.z = *reinterpret_cast<unsigned char*>(&f2);
    o.w = *reinterpret_cast<unsigned char*>(&f3);
    int kp = (lane >> 4) * 64 + ((lane >> 1) & 3) * 16 + ((lane >> 3) & 1) * 8
           + (lane & 1) * 4;
    *reinterpret_cast<uchar4*>(e + (size_t)row * DIM + kp) = o;

    if (lane == 0) {
        u[row] = ent / 4.04305127f;      // log(57)
        atomicAdd(&task_count[tasks[row]], 1);   // header pre-zeroed by memset
        scls[wave] = cls;
    }
    __syncthreads();
    if (threadIdx.x == 0) cls_part[blockIdx.x] = scls[0] + scls[1] + scls[2] + scls[3];
}

// ---- kernel 2: FULL sim matrix, col-direction reduction, ZERO atomics --------------
// Block: 128 rows x 256 cols; 8 waves = 2 row-halves(h) x 4 col-groups(cg);
// wave-tile 64x64. A (128x256B=32KB) staged once in LDS (chunk-XOR swizzled);
// B (64 cols) lives in 64 VGPR loaded up front; K-loop = 4x(4 ds_read_b128 +
// 32 MFMA), ONE barrier. Row-sums of the symmetric matrix are obtained as
// COLUMN sums (reg-local over rows + shfl 16/32 only: 24 shfl/wave vs 120).
// Per col j this block accumulates T=sum e^s (excl diag), P=sum_same-task e^s,
// S=sum_same-task s over its 128 rows -> partial[q][bm][j], unique writer.
__global__ __launch_bounds__(512, 2) void k_negsum(
        const unsigned char* __restrict__ E, const int* __restrict__ tasks,
        float* __restrict__ partial) {
    __shared__ unsigned char Asm[128 * 256];   // 32 KB
    __shared__ unsigned char ts[128];          // row tasks as u8 (NTASK<256)
    __shared__ float scr[3][256];              // h=1 partials for combine

    // XCD swizzle (2048 % 8 == 0 -> bijective); consecutive swz share bm (A L2 reuse)
    int b = (blockIdx.x & 7) * (2048 / 8) + (blockIdx.x >> 3);
    int bm = b >> 5;                     // 0..63
    int bn = b & 31;                     // 0..31
    int m0 = bm * 128, n0 = bn * 256;
    bool hasdiag = (bn == (bm >> 1));    // rows [m0,m0+128) inside cols [n0,n0+256)

    int tid = threadIdx.x;
    int w = tid >> 6, lane = tid & 63;
    int h = w >> 2, cg = w & 3;
    int g = lane >> 4, lr = lane & 15;
    int cbase = n0 + cg * 64;

    // ---- B: this wave's 64 cols, full K, in regs (16 x b128 = 64 VGPR) ----
    lgx2 bfr[4][4];
    #pragma unroll
    for (int f = 0; f < 4; ++f)
        #pragma unroll
        for (int t = 0; t < 4; ++t)
            bfr[f][t] = *reinterpret_cast<const lgx2*>(
                E + (size_t)(cbase + f * 16 + lr) * DIM + t * 64 + g * 16);

    // ---- A: stage 128 rows once, chunk-XOR (kb^(row&7)) on global source ----
    #pragma unroll
    for (int it = 0; it < 4; ++it) {
        int flat = it * 512 + tid;       // 16B chunk 0..2047
        int row = flat >> 4, kb = flat & 15;
        int kbs = kb ^ (row & 7);        // XOR only low 3 bits (row&7 < 8)
        gload_lds16(E + (size_t)(m0 + row) * DIM + kbs * 16,
                    Asm + (size_t)(it * 512 + w * 64) * 16);
    }
    if (tid < 128) ts[tid] = (unsigned char)tasks[m0 + tid];
    __syncthreads();                     // the only pre-epilogue barrier

    f32x4 acc[4][4] = {};
    #pragma unroll
    for (int t = 0; t < 4; ++t) {
        lgx2 a[4];
        #pragma unroll
        for (int m = 0; m < 4; ++m)
            a[m] = *reinterpret_cast<const lgx2*>(
                Asm + (size_t)(h * 64 + m * 16 + lr) * 256
                    + (((t * 4 + g) ^ (lr & 7)) * 16));
        #pragma unroll
        for (int m = 0; m < 4; ++m)
            #pragma unroll
            for (int f = 0; f < 4; ++f) {
                acc[m][f] = __builtin_amdgcn_mfma_f32_16x16x32_fp8_fp8(
                    a[m][0], bfr[f][t][0], acc[m][f], 0, 0, 0);
                acc[m][f] = __builtin_amdgcn_mfma_f32_16x16x32_fp8_fp8(
                    a[m][1], bfr[f][t][1], acc[m][f], 0, 0, 0);
            }
    }

    // ---- epilogue: per-lane col sums over this wave's 64 rows ----
    int ctb[4];
    #pragma unroll
    for (int f = 0; f < 4; ++f) ctb[f] = tasks[cbase + f * 16 + lr];
    float T[4] = {}, P[4] = {}, S[4] = {};
    #pragma unroll
    for (int m = 0; m < 4; ++m) {
        unsigned rt4 = *reinterpret_cast<const unsigned*>(&ts[h * 64 + m * 16 + g * 4]);
        #pragma unroll
        for (int r = 0; r < 4; ++r) {
            int rt = (rt4 >> (8 * r)) & 255;
            #pragma unroll
            for (int f = 0; f < 4; ++f) {
                float sv = acc[m][f][r] * INV_T;
                float ev = __expf(sv);
                bool keep = true;
                if (hasdiag)
                    keep = (m0 + h * 64 + m * 16 + g * 4 + r) != (cbase + f * 16 + lr);
                bool eq = (rt == ctb[f]) && keep;
                T[f] += keep ? ev : 0.0f;
                P[f] += eq ? ev : 0.0f;
                S[f] += eq ? sv : 0.0f;
            }
        }
    }
    #pragma unroll
    for (int f = 0; f < 4; ++f) {        // cross-g butterfly: 2 shfl per quantity
        T[f] += __shfl_xor(T[f], 16); T[f] += __shfl_xor(T[f], 32);
        P[f] += __shfl_xor(P[f], 16); P[f] += __shfl_xor(P[f], 32);
        S[f] += __shfl_xor(S[f], 16); S[f] += __shfl_xor(S[f], 32);
    }
    if (h == 1 && g == 0) {
        #pragma unroll
        for (int f = 0; f < 4; ++f) {
            int c = cg * 64 + f * 16 + lr;
            scr[0][c] = T[f]; scr[1][c] = P[f]; scr[2][c] = S[f];
        }
    }
    __syncthreads();
    if (h == 0 && g == 0) {
        #pragma unroll
        for (int f = 0; f < 4; ++f) {
            int c = cg * 64 + f * 16 + lr;
            size_t sl = (size_t)bm * BSZ + n0 + c;
            partial[sl]                        = T[f] + scr[0][c];
            partial[(size_t)GBM * BSZ + sl]    = P[f] + scr[1][c];
            partial[(size_t)2 * GBM * BSZ + sl] = S[f] + scr[2][c];
        }
    }
}

// ---- kernel 3: per-col finalize + ticket-fused combine -----------------------------
// neg_j = T_j - P_j; contr_j = u_j*((c-1)*log(C) + P_j/C - S_j), C = neg_j + 1e-8
// (first-order expansion validated R9, absmax 0).
__global__ __launch_bounds__(256) void k_finalize(
        const int* __restrict__ tasks, const int* __restrict__ task_count,
        const float* __restrict__ partial, const float* __restrict__ u,
        const float* __restrict__ cls_part, float* __restrict__ contr_total,
        int* __restrict__ ticket, float* __restrict__ out) {
    __shared__ float sp[4];
    __shared__ int lastflag;
    int tid = threadIdx.x, wave = tid >> 6, lane = tid & 63;
    int j = blockIdx.x * 256 + tid;
    const float* pT = partial;
    const float* pP = partial + (size_t)GBM * BSZ;
    const float* pS = partial + (size_t)2 * GBM * BSZ;
    float T = 0.0f, P = 0.0f, S = 0.0f;
    #pragma unroll 8
    for (int bm = 0; bm < GBM; ++bm) {
        T += pT[(size_t)bm * BSZ + j];
        P += pP[(size_t)bm * BSZ + j];
        S += pS[(size_t)bm * BSZ + j];
    }
    float v = 0.0f;
    int c = task_count[tasks[j]];
    if (c >= 2 && c < BSZ) {
        float C = (T - P) + 1e-8f;
        v = u[j] * ((float)(c - 1) * logf(C) + P / C - S);
    }
    #pragma unroll
    for (int s = 1; s < 64; s <<= 1) v += __shfl_xor(v, s);
    if (lane == 0) sp[wave] = v;
    __syncthreads();
    if (tid == 0) {
        atomicAdd(contr_total, sp[0] + sp[1] + sp[2] + sp[3]);
        __threadfence();
        lastflag = (atomicAdd(ticket, 1) == FIN_GRID - 1);
    }
    __syncthreads();
    if (lastflag) {                      // last block: all contributions landed
        __threadfence();
        float c1 = 0.0f;
        for (int q = tid; q < BSZ / 4; q += 256) c1 += cls_part[q];
        long long cn = 0;
        if (tid < NTASK) {
            int cc = task_count[tid];
            if (cc >= 2 && cc < BSZ) cn = (long long)cc * (cc - 1);
        }
        #pragma unroll
        for (int s = 1; s < 64; s <<= 1) { c1 += __shfl_xor(c1, s); cn += __shfl_xor(cn, s); }
        __shared__ float scf[4]; __shared__ long long snf[4];
        if (lane == 0) { scf[wave] = c1; snf[wave] = cn; }
        __syncthreads();
        if (tid == 0) {
            float cls = (scf[0] + scf[1] + scf[2] + scf[3]) / (float)BSZ;
            long long cnt = snf[0] + snf[1] + snf[2] + snf[3];
            float con = __hip_atomic_load(contr_total, __ATOMIC_ACQUIRE,
                                          __HIP_MEMORY_SCOPE_AGENT);
            out[0] = 0.7f * cls + 0.3f * (cnt > 0 ? con / (float)cnt : 0.0f);
        }
    }
}

extern "C" void kernel_launch(void* const* d_in, const int* in_sizes, int n_in,
                              void* d_out, int out_size, void* d_ws, size_t ws_size,
                              hipStream_t stream) {
    const float* logits = (const float*)d_in[0];
    const float* emb    = (const float*)d_in[1];
    const int*   labels = (const int*)d_in[2];
    const int*   tasks  = (const int*)d_in[3];
    float* out = (float*)d_out;

    char* ws = (char*)d_ws;
    // layout (4B units):
    // header[512]: [0]=contr_total [1]=ticket [64..]=task_count
    // u[BSZ], cls_part[2048], partial[3*64*8192] (6 MB), E fp8[BSZ*DIM] (2 MB)
    float* contr_total = (float*)ws;
    int*   ticket      = (int*)ws + 1;
    int*   task_count  = (int*)ws + 64;
    float* u           = (float*)ws + 512;
    float* cls_part    = u + BSZ;
    float* partial     = cls_part + 2048;
    unsigned char* e   = (unsigned char*)(partial + (size_t)3 * GBM * BSZ);

    // zero header only (contr/ticket/task_count); partial has unique writers
    hipMemsetAsync(ws, 0, 512 * 4, stream);

    k_prep    <<<BSZ / 4,     256, 0, stream>>>(logits, emb, labels, tasks, u, cls_part,
                                                task_count, e);
    k_negsum  <<<GBM * GBN,   512, 0, stream>>>(e, tasks, partial);
    k_finalize<<<FIN_GRID,    256, 0, stream>>>(tasks, task_count, partial, u, cls_part,
                                                contr_total, ticket, out);
}